// Round 9
// baseline (25508.748 us; speedup 1.0000x reference)
//
#include <hip/hip_runtime.h>
#include <math.h>

// Seq2SeqRNN fp32.
// Encoder: sync-free persistent recurrence (r6, unchanged).
// Decoder r9: persistent kernel, 256 WGs x 512 threads (8 waves/CU).
//  - NO register prefetch rings (r8: spilled at VGPR=256, -60%).
//  - phase 4: h1T staged once/step to LDS; embT double-buffered in LDS
//    (32row x 128col = 16KB chunks): load chunk k+1 -> FMA chunk k -> ds_write
//    -> barrier. In-flight bytes live in LDS, not VGPRs.
//  - GRU weights streamed from L2 (persistent WGs keep rows hot), 2-way k-split.
//  - counting barrier + bypass-atomic state protocol (r7, proven).

typedef unsigned long long ull;
typedef float v2f __attribute__((ext_vector_type(2)));

#define DINL static __device__ __forceinline__

DINL float sigm(float x) { return 1.0f / (1.0f + expf(-x)); }
DINL float dot4f(float4 a, float4 b) { return a.x*b.x + a.y*b.y + a.z*b.z + a.w*b.w; }

DINL ull packmax(float x, int v) {
  unsigned u = __float_as_uint(x);
  u = (u & 0x80000000u) ? ~u : (u | 0x80000000u);
  return ((ull)u << 32) | (unsigned)(~v);  // ties -> smaller v wins
}
DINL ull umax64(ull a, ull b) { return a > b ? a : b; }

DINL float atl(const float* p) {
  unsigned u = __hip_atomic_load((const unsigned*)p, __ATOMIC_RELAXED,
                                 __HIP_MEMORY_SCOPE_AGENT);
  return __uint_as_float(u);
}
DINL void atsf(float* p, float v) {
  __hip_atomic_exchange((unsigned*)p, __float_as_uint(v), __ATOMIC_RELAXED,
                        __HIP_MEMORY_SCOPE_AGENT);
}
DINL ull atl64(const ull* p) {
  return __hip_atomic_load(p, __ATOMIC_RELAXED, __HIP_MEMORY_SCOPE_AGENT);
}
DINL void ats64(ull* p, ull v) {
  __hip_atomic_exchange(p, v, __ATOMIC_RELAXED, __HIP_MEMORY_SCOPE_AGENT);
}

// counting grid barrier: one fetch_add + tid0-only poll. grid = 256 WGs exactly.
DINL void gbar(unsigned* cnt, unsigned target, int tid) {
  asm volatile("s_waitcnt vmcnt(0)" ::: "memory");
  __syncthreads();
  if (tid == 0) {
    __hip_atomic_fetch_add(cnt, 1u, __ATOMIC_RELAXED, __HIP_MEMORY_SCOPE_AGENT);
    while (__hip_atomic_load(cnt, __ATOMIC_RELAXED, __HIP_MEMORY_SCOPE_AGENT) < target)
      __builtin_amdgcn_s_sleep(4);
  }
  __syncthreads();
}

// ---------------- embedding gather (300 = 75 float4)
__global__ __launch_bounds__(256) void k_embed(const float4* __restrict__ E,
                                               const int* __restrict__ inp,
                                               float4* __restrict__ out) {
  int i = blockIdx.x * 256 + threadIdx.x;
  if (i >= 8192 * 75) return;
  int row = i / 75, q = i - row * 75;
  out[i] = E[(size_t)inp[row] * 75 + q];
}

// ---------------- transpose B[c*R+r] = A[r*C+c]
__global__ __launch_bounds__(256) void k_transpose(const float* __restrict__ A,
                                                   float* __restrict__ B, int R, int C) {
  __shared__ float tile[32][33];
  int c0 = blockIdx.x * 32, r0 = blockIdx.y * 32;
  int tx = threadIdx.x & 31, ty = threadIdx.x >> 5;
  for (int i = 0; i < 32; i += 8) {
    int r = r0 + ty + i, c = c0 + tx;
    if (r < R && c < C) tile[ty + i][tx] = A[(size_t)r * C + c];
  }
  __syncthreads();
  for (int i = 0; i < 32; i += 8) {
    int c = c0 + ty + i, r = r0 + tx;
    if (c < C && r < R) B[(size_t)c * R + r] = tile[tx][ty + i];
  }
}

// ---------------- pack Whh[2][768][256] -> W2[2][128 kp][768 gc][2]
__global__ __launch_bounds__(256) void k_packW(const float* __restrict__ Whh,
                                               float* __restrict__ W2) {
  int i = blockIdx.x * 256 + threadIdx.x;
  if (i >= 196608) return;
  int d = i / 98304, r = i - d * 98304, kp = r / 768, gc = r - kp * 768;
  const float* src = Whh + (size_t)d * 196608 + (size_t)gc * 256 + kp * 2;
  float* dst = W2 + (size_t)i * 2;
  dst[0] = src[0];
  dst[1] = src[1];
}

// ---------------- fp32 GEMM-NT: C[n,m] = sum_k A[n,k]*B[m,k] + bias[m]
__global__ __launch_bounds__(256) void k_gemm128(const float* __restrict__ A,
                                                 const float* __restrict__ B,
                                                 const float* __restrict__ bias,
                                                 float* __restrict__ C,
                                                 int N, int M, int K) {
  __shared__ float As[8][132];
  __shared__ float Bs[8][132];
  const int tid = threadIdx.x;
  const int bn = blockIdx.x * 128, bm = blockIdx.y * 128;
  const int tn = (tid >> 4) << 3, tm = (tid & 15) << 3;
  const int r = tid & 127;
  const bool isB = tid >= 128;
  const float* src = isB ? (B + (size_t)(bm + r) * K) : (A + (size_t)(bn + r) * K);
  const bool rowok = isB ? (bm + r < M) : (bn + r < N);
  float acc[8][8] = {};
  for (int k0 = 0; k0 < K; k0 += 8) {
    float v[8];
    if (rowok && k0 + 8 <= K) {
      float4 p0 = *(const float4*)(src + k0);
      float4 p1 = *(const float4*)(src + k0 + 4);
      v[0]=p0.x; v[1]=p0.y; v[2]=p0.z; v[3]=p0.w;
      v[4]=p1.x; v[5]=p1.y; v[6]=p1.z; v[7]=p1.w;
    } else {
#pragma unroll
      for (int j = 0; j < 8; ++j) v[j] = (rowok && k0 + j < K) ? src[k0 + j] : 0.0f;
    }
    float (*dst)[132] = isB ? Bs : As;
#pragma unroll
    for (int j = 0; j < 8; ++j) dst[j][r] = v[j];
    __syncthreads();
#pragma unroll
    for (int kk = 0; kk < 8; ++kk) {
      float a[8], b[8];
      *(float4*)&a[0] = *(const float4*)&As[kk][tn];
      *(float4*)&a[4] = *(const float4*)&As[kk][tn + 4];
      *(float4*)&b[0] = *(const float4*)&Bs[kk][tm];
      *(float4*)&b[4] = *(const float4*)&Bs[kk][tm + 4];
#pragma unroll
      for (int i = 0; i < 8; ++i)
#pragma unroll
        for (int j = 0; j < 8; ++j) acc[i][j] += a[i] * b[j];
    }
    __syncthreads();
  }
#pragma unroll
  for (int i = 0; i < 8; ++i) {
    int row = bn + tn + i;
    if (row >= N) continue;
#pragma unroll
    for (int j = 0; j < 8; ++j) {
      int col = bm + tm + j;
      if (col < M) C[(size_t)row * M + col] = acc[i][j] + (bias ? bias[col] : 0.0f);
    }
  }
}

// ---------------- sync-free encoder recurrence (r6, unchanged)
__global__ __launch_bounds__(256) void k_enc_rec(
    const float* __restrict__ giF, const float* __restrict__ giB,
    const float* __restrict__ W2, const float* __restrict__ bhh,
    float* __restrict__ y) {
  const int b0 = blockIdx.x * 2;
  const int dir = blockIdx.y;
  const int c = threadIdx.x;
  const float* gi = dir ? giB : giF;
  const v2f* Wv = (const v2f*)(W2 + (size_t)dir * 196608);
  const float* bh = bhh + dir * 768;

  __shared__ __align__(16) float hls[2][2][258];
  for (int i = c; i < 2 * 2 * 258; i += 256) ((float*)hls)[i] = 0.0f;
  __syncthreads();

  const float bhr = bh[c], bhz = bh[256 + c], bhn = bh[512 + c];
  const int tt0 = dir ? 127 : 0;
  const float* g0p = gi + (size_t)tt0 * 49152 + (size_t)b0 * 768;
  float g0r = g0p[c], g0z = g0p[256 + c], g0n = g0p[512 + c];
  float g1r = g0p[768 + c], g1z = g0p[1024 + c], g1n = g0p[1280 + c];

  for (int t = 0; t < 128; ++t) {
    const int cu = t & 1;
    float p0r = 0, p0z = 0, p0n = 0, p1r = 0, p1z = 0, p1n = 0;
    if (t < 127) {
      const int tn_ = dir ? 126 - t : t + 1;
      const float* gp = gi + (size_t)tn_ * 49152 + (size_t)b0 * 768;
      p0r = gp[c]; p0z = gp[256 + c]; p0n = gp[512 + c];
      p1r = gp[768 + c]; p1z = gp[1024 + c]; p1n = gp[1280 + c];
    }
    v2f a0r = {0,0}, a0z = {0,0}, a0n = {0,0};
    v2f a1r = {0,0}, a1z = {0,0}, a1n = {0,0};
    const float* h0p = &hls[cu][0][0];
    const float* h1p = &hls[cu][1][0];
#pragma unroll 4
    for (int kp = 0; kp < 128; ++kp) {
      v2f wr = Wv[kp * 768 + c];
      v2f wz = Wv[kp * 768 + 256 + c];
      v2f wn = Wv[kp * 768 + 512 + c];
      v2f h0 = *(const v2f*)&h0p[kp * 2];
      v2f h1 = *(const v2f*)&h1p[kp * 2];
      a0r += h0 * wr; a0z += h0 * wz; a0n += h0 * wn;
      a1r += h1 * wr; a1z += h1 * wz; a1n += h1 * wn;
    }
    float r0 = sigm(g0r + a0r.x + a0r.y + bhr);
    float z0 = sigm(g0z + a0z.x + a0z.y + bhz);
    float n0 = tanhf(g0n + r0 * (a0n.x + a0n.y + bhn));
    float h0new = (1.f - z0) * n0 + z0 * h0p[c];
    float r1 = sigm(g1r + a1r.x + a1r.y + bhr);
    float z1 = sigm(g1z + a1z.x + a1z.y + bhz);
    float n1 = tanhf(g1n + r1 * (a1n.x + a1n.y + bhn));
    float h1new = (1.f - z1) * n1 + z1 * h1p[c];
    hls[cu ^ 1][0][c] = h0new;
    hls[cu ^ 1][1][c] = h1new;
    const int tw = dir ? 127 - t : t;
    float* yp = y + (size_t)tw * 32768 + (size_t)b0 * 512 + dir * 256 + c;
    yp[0] = h0new;
    yp[512] = h1new;
    g0r = p0r; g0z = p0z; g0n = p0n; g1r = p1r; g1z = p1z; g1n = p1n;
    __syncthreads();
  }
}

// ---------------- hcat[2][64][512]
__global__ __launch_bounds__(256) void k_hcat(const float* __restrict__ x1,
                                              const float* __restrict__ encout,
                                              float* __restrict__ hcat) {
  int i = blockIdx.x * 256 + threadIdx.x;
  int l = i >> 15, r = i & 32767, b = r >> 9, d = r & 511;
  const float* src = l ? encout : x1;
  int ts = (d < 256) ? 127 : 0;
  hcat[i] = src[((size_t)(ts << 6) + b) * 512 + d];
}

// ---------------- GRU cell phase, weights streamed from L2, 2-way k-split.
// 512 threads: cl=tid&15 (16 cols), bl=(tid>>4)&15 (16 batches), ks=tid>>8.
DINL void gru_stream(int cch, int bch, int tid,
                     const float* __restrict__ xin, const float* __restrict__ hin,
                     float* __restrict__ hout, float* __restrict__ houtT,
                     const float* __restrict__ Wih, const float* __restrict__ Whh,
                     const float* __restrict__ bih, const float* __restrict__ bhh,
                     float* C) {
  float* xs = C;            // [16][300]
  float* hs = C + 4800;     // [16][300]
  float* part = C + 9600;   // [6][256]
  const int b0 = bch * 16;
  for (int i = tid; i < 9600; i += 512) {
    int j = (i < 4800) ? i : i - 4800;
    int row = j / 300, q = j - row * 300;
    C[i] = atl(((i < 4800) ? xin : hin) + (size_t)(b0 + row) * 300 + q);
  }
  __syncthreads();
  const int cl = tid & 15, bl = (tid >> 4) & 15, ks = tid >> 8;
  const int c = cch * 16 + cl, bq = b0 + bl;
  const bool valid = (c < 300);
  float a0 = 0, a1 = 0, a2 = 0, a3 = 0, a4 = 0, a5 = 0;
  if (valid) {
    const int q0 = ks ? 38 : 0, q1 = ks ? 75 : 38;
    const float4* xr = (const float4*)(xs + bl * 300);
    const float4* hr = (const float4*)(hs + bl * 300);
    const float4* w0 = (const float4*)(Wih + (size_t)c * 300);
    const float4* w1 = (const float4*)(Wih + (size_t)(300 + c) * 300);
    const float4* w2 = (const float4*)(Wih + (size_t)(600 + c) * 300);
    const float4* w3 = (const float4*)(Whh + (size_t)c * 300);
    const float4* w4 = (const float4*)(Whh + (size_t)(300 + c) * 300);
    const float4* w5 = (const float4*)(Whh + (size_t)(600 + c) * 300);
    for (int q = q0; q < q1; ++q) {
      float4 xv = xr[q], hv = hr[q];
      a0 += dot4f(xv, w0[q]);
      a1 += dot4f(xv, w1[q]);
      a2 += dot4f(xv, w2[q]);
      a3 += dot4f(hv, w3[q]);
      a4 += dot4f(hv, w4[q]);
      a5 += dot4f(hv, w5[q]);
    }
  }
  const int idx = bl * 16 + cl;
  if (ks == 1) {
    part[idx] = a0; part[256 + idx] = a1; part[512 + idx] = a2;
    part[768 + idx] = a3; part[1024 + idx] = a4; part[1280 + idx] = a5;
  }
  __syncthreads();
  if (ks == 0 && valid) {
    float gir = a0 + part[idx]        + bih[c];
    float giz = a1 + part[256 + idx]  + bih[300 + c];
    float gin = a2 + part[512 + idx]  + bih[600 + c];
    float ghr = a3 + part[768 + idx]  + bhh[c];
    float ghz = a4 + part[1024 + idx] + bhh[300 + c];
    float ghn = a5 + part[1280 + idx] + bhh[600 + c];
    float r = sigm(gir + ghr), z = sigm(giz + ghz);
    float n = tanhf(gin + r * ghn);
    float hnew = (1.f - z) * n + z * hs[bl * 300 + c];
    atsf(&hout[(size_t)bq * 300 + c], hnew);
    if (houtT) atsf(&houtT[(size_t)c * 64 + bq], hnew);
  }
  __syncthreads();
}

// ---------------- persistent decoder: all 32 steps, 256 WGs x 512 threads.
__global__ __launch_bounds__(512) void k_dec_all(
    float* __restrict__ dech, float* __restrict__ h1T, float* __restrict__ xdec,
    ull* __restrict__ bests, unsigned* __restrict__ cnt,
    const float* __restrict__ w1e, const float* __restrict__ encout,
    const float* __restrict__ l2W, const float* __restrict__ l2b,
    const float* __restrict__ l3W, const float* __restrict__ l3b,
    const float* __restrict__ Vatt, const float* __restrict__ embdec,
    const float* __restrict__ dWih, const float* __restrict__ dWhh,
    const float* __restrict__ dbih, const float* __restrict__ dbhh,
    const float* __restrict__ embT, const float* __restrict__ outb,
    float* __restrict__ out) {
  const int wg = blockIdx.x, tid = threadIdx.x;
  __shared__ __align__(16) float4 ebuf[2][1024];  // 32 KB: embT chunk dbuf
  __shared__ __align__(16) float C[19200];        // 76.8 KB: h / gru / att / sacc

  const int grole = (wg < 76) ? wg : ((wg < 152) ? wg - 76 : 0);
  const int cch = grole % 19, bch = grole / 19;

  unsigned tgt = 0;
  for (int t = 0; t < 32; ++t) {
    const int cur_ = t & 1;
    float* hc = dech + cur_ * 38400;
    float* hn = dech + (cur_ ^ 1) * 38400;

    // ---- phase 1: attention + x build (wg < 64, one WG per batch)
    if (wg < 64) {
      const int b = wg;
      float* h1s = C;
      float* w2h = C + 304;
      float* eXa = C + 608;
      float* aa  = C + 1424;
      float* red = C + 1552;
      ull* redb  = (ull*)(C + 1680);

      if (tid < 128) {
        ull m = 0ULL;
        if (t > 0) {
          m = atl64(&bests[(size_t)tid * 64 + b]);
          if (tid + 128 < 250) m = umax64(m, atl64(&bests[(size_t)(tid + 128) * 64 + b]));
        }
        redb[tid] = m;
      }
      if (tid < 300) h1s[tid] = atl(hc + 19200 + b * 300 + tid);
      __syncthreads();
      for (int s = 64; s > 0; s >>= 1) {
        if (tid < s) redb[tid] = umax64(redb[tid], redb[tid + s]);
        __syncthreads();
      }
      const int ib = (t > 0) ? (int)(~(unsigned)(redb[0] & 0xFFFFFFFFULL)) : 0;

      if (tid < 300) {
        const float4* wr = (const float4*)(l2W + (size_t)tid * 300);
        const float4* hr = (const float4*)h1s;
        float acc = l2b[tid];
        for (int q = 0; q < 75; ++q) acc += dot4f(wr[q], hr[q]);
        w2h[tid] = acc;
      }
      __syncthreads();

      if (tid < 128) {
        const float4* wp = (const float4*)(w1e + ((size_t)(tid << 6) + b) * 300);
        const float4* vp = (const float4*)Vatt;
        const float4* hp = (const float4*)w2h;
        float acc = 0.f;
        for (int q = 0; q < 75; ++q) {
          float4 w = wp[q], h = hp[q], v = vp[q];
          acc += tanhf(w.x + h.x) * v.x + tanhf(w.y + h.y) * v.y +
                 tanhf(w.z + h.z) * v.z + tanhf(w.w + h.w) * v.w;
        }
        aa[tid] = acc;
        red[tid] = acc;
      }
      __syncthreads();
      for (int s = 64; s > 0; s >>= 1) {
        if (tid < s) red[tid] = fmaxf(red[tid], red[tid + s]);
        __syncthreads();
      }
      float mx = red[0];
      __syncthreads();
      if (tid < 128) {
        float ex = expf(aa[tid] - mx);
        aa[tid] = ex;
        red[tid] = ex;
      }
      __syncthreads();
      for (int s = 64; s > 0; s >>= 1) {
        if (tid < s) red[tid] += red[tid + s];
        __syncthreads();
      }
      float inv = 1.0f / red[0];
      __syncthreads();
      if (tid < 128) aa[tid] *= inv;
      if (tid < 300) eXa[tid] = embdec[(size_t)ib * 300 + tid];
      __syncthreads();

      // Xa: 512 cols, one per thread
      {
        const float* ebase = encout + (size_t)b * 512 + tid;
        float acc = 0.f;
        for (int s = 0; s < 128; ++s) acc += aa[s] * ebase[(size_t)s * 32768];
        eXa[300 + tid] = acc;
      }
      __syncthreads();

      if (tid < 300) {
        const float4* wr = (const float4*)(l3W + (size_t)tid * 812);
        const float4* xr = (const float4*)eXa;
        float acc = l3b[tid];
        for (int q = 0; q < 203; ++q) acc += dot4f(wr[q], xr[q]);
        atsf(&xdec[b * 300 + tid], acc);
      }
      __syncthreads();
    }
    gbar(cnt, 256u * (++tgt), tid);

    // ---- phase 2: GRU cell 0 (wg < 76)
    if (wg < 76)
      gru_stream(cch, bch, tid, xdec, hc, hn, nullptr,
                 dWih, dWhh, dbih, dbhh, C);
    gbar(cnt, 256u * (++tgt), tid);

    // ---- phase 3: GRU cell 1 (wg 76..151, +h1T)
    if (wg >= 76 && wg < 152)
      gru_stream(cch, bch, tid, hn, hc + 19200, hn + 19200, h1T,
                 dWih + 270000, dWhh + 270000, dbih + 900, dbhh + 900, C);
    gbar(cnt, 256u * (++tgt), tid);

    // ---- phase 4: logits + argmax partials (wg < 250, 128 v-cols)
    if (wg < 250) {
      const int v0 = wg * 128;
      const int vq = tid & 31, bo = tid >> 5;  // 32 col-quads x 16 batch-quads
      // stage full h1T into C + chunk 0 of embT into ebuf[0]
      for (int i = tid; i < 19200; i += 512) C[i] = atl(h1T + i);
      {
        const int u0 = tid * 2, u1 = u0 + 1;
        float4 s0 = *(const float4*)(embT + (size_t)(u0 >> 5) * 32000 + v0 + ((u0 & 31) << 2));
        float4 s1 = *(const float4*)(embT + (size_t)(u1 >> 5) * 32000 + v0 + ((u1 & 31) << 2));
        ebuf[0][u0] = s0;
        ebuf[0][u1] = s1;
      }
      __syncthreads();

      float acc[4][4] = {};
      int cur = 0;
      for (int kc = 0; kc < 10; ++kc) {
        const int k0 = kc << 5;
        const int nrows = (kc < 9) ? 32 : 12;
        float4 s0, s1;
        bool h0 = false, h1 = false;
        if (kc < 9) {
          const int nk0 = k0 + 32;
          const int nun = ((kc < 8) ? 32 : 12) << 5;
          const int u0 = tid * 2, u1 = u0 + 1;
          if (u0 < nun) {
            s0 = *(const float4*)(embT + (size_t)(nk0 + (u0 >> 5)) * 32000 + v0 + ((u0 & 31) << 2));
            h0 = true;
          }
          if (u1 < nun) {
            s1 = *(const float4*)(embT + (size_t)(nk0 + (u1 >> 5)) * 32000 + v0 + ((u1 & 31) << 2));
            h1 = true;
          }
        }
        for (int k = 0; k < nrows; ++k) {
          float4 ev = ebuf[cur][(k << 5) + vq];
          float4 hv = *(const float4*)&C[((k0 + k) << 6) + (bo << 2)];
          acc[0][0] += hv.x * ev.x; acc[0][1] += hv.x * ev.y;
          acc[0][2] += hv.x * ev.z; acc[0][3] += hv.x * ev.w;
          acc[1][0] += hv.y * ev.x; acc[1][1] += hv.y * ev.y;
          acc[1][2] += hv.y * ev.z; acc[1][3] += hv.y * ev.w;
          acc[2][0] += hv.z * ev.x; acc[2][1] += hv.z * ev.y;
          acc[2][2] += hv.z * ev.z; acc[2][3] += hv.z * ev.w;
          acc[3][0] += hv.w * ev.x; acc[3][1] += hv.w * ev.y;
          acc[3][2] += hv.w * ev.z; acc[3][3] += hv.w * ev.w;
        }
        if (h0) ebuf[cur ^ 1][tid * 2] = s0;
        if (h1) ebuf[cur ^ 1][tid * 2 + 1] = s1;
        __syncthreads();
        cur ^= 1;
      }

      // epilogue: write logits + LDS argmax partials (C reused as sacc[128][65])
      float* sacc = C;
      float4 ob = *(const float4*)(outb + v0 + (vq << 2));
      float* outp = out + (size_t)t * 2048000;
#pragma unroll
      for (int i = 0; i < 4; ++i) {
        const int b = (bo << 2) + i;
        float4 r;
        r.x = acc[i][0] + ob.x; r.y = acc[i][1] + ob.y;
        r.z = acc[i][2] + ob.z; r.w = acc[i][3] + ob.w;
        *(float4*)(outp + (size_t)b * 32000 + v0 + (vq << 2)) = r;
        sacc[((vq << 2) + 0) * 65 + b] = r.x;
        sacc[((vq << 2) + 1) * 65 + b] = r.y;
        sacc[((vq << 2) + 2) * 65 + b] = r.z;
        sacc[((vq << 2) + 3) * 65 + b] = r.w;
      }
      __syncthreads();
      if (tid < 64) {
        ull best = 0ULL;
#pragma unroll 4
        for (int v = 0; v < 128; ++v)
          best = umax64(best, packmax(sacc[v * 65 + tid], v0 + v));
        ats64(&bests[(size_t)wg * 64 + tid], best);
      }
      __syncthreads();
    }
    if (t < 31) gbar(cnt, 256u * (++tgt), tid);
  }
}

extern "C" void kernel_launch(void* const* d_in, const int* in_sizes, int n_in,
                              void* d_out_v, int out_size, void* d_ws, size_t ws_size,
                              hipStream_t stream) {
  (void)in_sizes; (void)n_in; (void)out_size; (void)ws_size;
  const float* emb_enc = (const float*)d_in[0];
  const float* eWih0   = (const float*)d_in[1];
  const float* eWhh0   = (const float*)d_in[2];
  const float* ebih0   = (const float*)d_in[3];
  const float* ebhh0   = (const float*)d_in[4];
  const float* eWih1   = (const float*)d_in[5];
  const float* eWhh1   = (const float*)d_in[6];
  const float* ebih1   = (const float*)d_in[7];
  const float* ebhh1   = (const float*)d_in[8];
  const float* Wout    = (const float*)d_in[9];
  const float* emb_dec = (const float*)d_in[10];
  const float* dWih    = (const float*)d_in[11];
  const float* dWhh    = (const float*)d_in[12];
  const float* dbih    = (const float*)d_in[13];
  const float* dbhh    = (const float*)d_in[14];
  const float* W1      = (const float*)d_in[15];
  const float* l2W     = (const float*)d_in[16];
  const float* l2b     = (const float*)d_in[17];
  const float* l3W     = (const float*)d_in[18];
  const float* l3b     = (const float*)d_in[19];
  const float* Vatt    = (const float*)d_in[20];
  const float* outb    = (const float*)d_in[21];
  const int* inp       = (const int*)d_in[22];
  float* d_out = (float*)d_out_v;

  float* ws = (float*)d_ws;
  size_t off = 0;
  auto take = [&](size_t n) { float* p = ws + off; off += (n + 3) & ~(size_t)3; return p; };
  float* embT   = take((size_t)300 * 32000);
  float* encout = take((size_t)8192 * 512);
  float* w1e    = take((size_t)8192 * 300);
  float* W1T    = take((size_t)300 * 512);
  float* hcat   = take((size_t)128 * 512);
  float* dech   = take((size_t)2 * 2 * 64 * 300);
  float* h1T    = take((size_t)300 * 64);
  float* xdec   = take((size_t)64 * 300);
  ull* bests    = (ull*)take((size_t)250 * 64 * 2);
  unsigned* cnt = (unsigned*)take((size_t)32);

  // encoder scratch in d_out (dead before decoder writes)
  float* emb  = d_out;
  float* gi0f = emb + 2457600;
  float* gi0b = gi0f + 6291456;
  float* x1   = gi0b + 6291456;
  float* gi1f = x1 + 4194304;
  float* gi1b = gi1f + 6291456;
  float* W2L0 = d_out + 33554432;
  float* W2L1 = W2L0 + 393216;

  hipMemsetAsync(cnt, 0, 32 * sizeof(unsigned), stream);

  k_embed<<<2400, 256, 0, stream>>>((const float4*)emb_enc, inp, (float4*)emb);
  k_transpose<<<dim3(10, 16), 256, 0, stream>>>(W1, W1T, 512, 300);
  k_transpose<<<dim3(10, 1000), 256, 0, stream>>>(emb_dec, embT, 32000, 300);
  k_packW<<<768, 256, 0, stream>>>(eWhh0, W2L0);
  k_packW<<<768, 256, 0, stream>>>(eWhh1, W2L1);

  // encoder layer 0
  k_gemm128<<<dim3(64, 6), 256, 0, stream>>>(emb, eWih0, ebih0, gi0f, 8192, 768, 300);
  k_gemm128<<<dim3(64, 6), 256, 0, stream>>>(emb, eWih0 + 230400, ebih0 + 768, gi0b, 8192, 768, 300);
  k_enc_rec<<<dim3(32, 2), 256, 0, stream>>>(gi0f, gi0b, W2L0, ebhh0, x1);

  // encoder layer 1
  k_gemm128<<<dim3(64, 6), 256, 0, stream>>>(x1, eWih1, ebih1, gi1f, 8192, 768, 512);
  k_gemm128<<<dim3(64, 6), 256, 0, stream>>>(x1, eWih1 + 393216, ebih1 + 768, gi1b, 8192, 768, 512);
  k_enc_rec<<<dim3(32, 2), 256, 0, stream>>>(gi1f, gi1b, W2L1, ebhh1, encout);

  // encoder epilogue
  k_hcat<<<256, 256, 0, stream>>>(x1, encout, hcat);
  k_gemm128<<<dim3(1, 3), 256, 0, stream>>>(hcat, Wout, nullptr, dech, 128, 300, 512);
  k_gemm128<<<dim3(64, 3), 256, 0, stream>>>(encout, W1T, nullptr, w1e, 8192, 300, 512);

  // persistent decoder
  k_dec_all<<<256, 512, 0, stream>>>(dech, h1T, xdec, bests, cnt,
                                     w1e, encout, l2W, l2b, l3W, l3b,
                                     Vatt, emb_dec, dWih, dWhh, dbih, dbhh,
                                     embT, outb, d_out);
}

// Round 10
// 11283.015 us; speedup vs baseline: 2.2608x; 2.2608x over previous
//
#include <hip/hip_runtime.h>
#include <math.h>

// Seq2SeqRNN fp32.
// Encoder: sync-free persistent recurrence (r6, unchanged).
// Decoder r10: revert to r7's 256-thread persistent structure (r9's 512-thread
// variant thrashed L2: 19GB fetch from 16-way-redundant weight scatter).
// Phase 4 rebuilt on global_load_lds double-buffering: embT staged to LDS in
// 16KB chunks, fire-and-forget (16B/lane direct-to-LDS), compute overlaps the
// stream. r7 counters showed phase 4 = one embT pass/step at 214 GB/s
// latency-bound = ~180us/step of the 236us/step total.

typedef unsigned long long ull;
typedef float v2f __attribute__((ext_vector_type(2)));

#define DINL static __device__ __forceinline__

DINL float sigm(float x) { return 1.0f / (1.0f + expf(-x)); }
DINL float dot4f(float4 a, float4 b) { return a.x*b.x + a.y*b.y + a.z*b.z + a.w*b.w; }

DINL ull packmax(float x, int v) {
  unsigned u = __float_as_uint(x);
  u = (u & 0x80000000u) ? ~u : (u | 0x80000000u);
  return ((ull)u << 32) | (unsigned)(~v);  // ties -> smaller v wins
}
DINL ull umax64(ull a, ull b) { return a > b ? a : b; }

DINL float atl(const float* p) {
  unsigned u = __hip_atomic_load((const unsigned*)p, __ATOMIC_RELAXED,
                                 __HIP_MEMORY_SCOPE_AGENT);
  return __uint_as_float(u);
}
DINL void atsf(float* p, float v) {
  __hip_atomic_exchange((unsigned*)p, __float_as_uint(v), __ATOMIC_RELAXED,
                        __HIP_MEMORY_SCOPE_AGENT);
}
DINL ull atl64(const ull* p) {
  return __hip_atomic_load(p, __ATOMIC_RELAXED, __HIP_MEMORY_SCOPE_AGENT);
}
DINL void ats64(ull* p, ull v) {
  __hip_atomic_exchange(p, v, __ATOMIC_RELAXED, __HIP_MEMORY_SCOPE_AGENT);
}

// async global->LDS: 16B per lane, LDS dest = wave-uniform base + lane*16
DINL void gl_lds16(const float* gaddr, float* laddr) {
  __builtin_amdgcn_global_load_lds(
      (const __attribute__((address_space(1))) unsigned*)gaddr,
      (__attribute__((address_space(3))) unsigned*)laddr, 16, 0, 0);
}

// counting grid barrier: one fetch_add + tid0-only poll. grid = 256 WGs exactly.
DINL void gbar(unsigned* cnt, unsigned target, int tid) {
  asm volatile("s_waitcnt vmcnt(0)" ::: "memory");
  __syncthreads();
  if (tid == 0) {
    __hip_atomic_fetch_add(cnt, 1u, __ATOMIC_RELAXED, __HIP_MEMORY_SCOPE_AGENT);
    while (__hip_atomic_load(cnt, __ATOMIC_RELAXED, __HIP_MEMORY_SCOPE_AGENT) < target)
      __builtin_amdgcn_s_sleep(4);
  }
  __syncthreads();
}

// ---------------- embedding gather (300 = 75 float4)
__global__ __launch_bounds__(256) void k_embed(const float4* __restrict__ E,
                                               const int* __restrict__ inp,
                                               float4* __restrict__ out) {
  int i = blockIdx.x * 256 + threadIdx.x;
  if (i >= 8192 * 75) return;
  int row = i / 75, q = i - row * 75;
  out[i] = E[(size_t)inp[row] * 75 + q];
}

// ---------------- transpose B[c*R+r] = A[r*C+c]
__global__ __launch_bounds__(256) void k_transpose(const float* __restrict__ A,
                                                   float* __restrict__ B, int R, int C) {
  __shared__ float tile[32][33];
  int c0 = blockIdx.x * 32, r0 = blockIdx.y * 32;
  int tx = threadIdx.x & 31, ty = threadIdx.x >> 5;
  for (int i = 0; i < 32; i += 8) {
    int r = r0 + ty + i, c = c0 + tx;
    if (r < R && c < C) tile[ty + i][tx] = A[(size_t)r * C + c];
  }
  __syncthreads();
  for (int i = 0; i < 32; i += 8) {
    int c = c0 + ty + i, r = r0 + tx;
    if (c < C && r < R) B[(size_t)c * R + r] = tile[tx][ty + i];
  }
}

// ---------------- pack Whh[2][768][256] -> W2[2][128 kp][768 gc][2]
__global__ __launch_bounds__(256) void k_packW(const float* __restrict__ Whh,
                                               float* __restrict__ W2) {
  int i = blockIdx.x * 256 + threadIdx.x;
  if (i >= 196608) return;
  int d = i / 98304, r = i - d * 98304, kp = r / 768, gc = r - kp * 768;
  const float* src = Whh + (size_t)d * 196608 + (size_t)gc * 256 + kp * 2;
  float* dst = W2 + (size_t)i * 2;
  dst[0] = src[0];
  dst[1] = src[1];
}

// ---------------- fp32 GEMM-NT: C[n,m] = sum_k A[n,k]*B[m,k] + bias[m]
__global__ __launch_bounds__(256) void k_gemm128(const float* __restrict__ A,
                                                 const float* __restrict__ B,
                                                 const float* __restrict__ bias,
                                                 float* __restrict__ C,
                                                 int N, int M, int K) {
  __shared__ float As[8][132];
  __shared__ float Bs[8][132];
  const int tid = threadIdx.x;
  const int bn = blockIdx.x * 128, bm = blockIdx.y * 128;
  const int tn = (tid >> 4) << 3, tm = (tid & 15) << 3;
  const int r = tid & 127;
  const bool isB = tid >= 128;
  const float* src = isB ? (B + (size_t)(bm + r) * K) : (A + (size_t)(bn + r) * K);
  const bool rowok = isB ? (bm + r < M) : (bn + r < N);
  float acc[8][8] = {};
  for (int k0 = 0; k0 < K; k0 += 8) {
    float v[8];
    if (rowok && k0 + 8 <= K) {
      float4 p0 = *(const float4*)(src + k0);
      float4 p1 = *(const float4*)(src + k0 + 4);
      v[0]=p0.x; v[1]=p0.y; v[2]=p0.z; v[3]=p0.w;
      v[4]=p1.x; v[5]=p1.y; v[6]=p1.z; v[7]=p1.w;
    } else {
#pragma unroll
      for (int j = 0; j < 8; ++j) v[j] = (rowok && k0 + j < K) ? src[k0 + j] : 0.0f;
    }
    float (*dst)[132] = isB ? Bs : As;
#pragma unroll
    for (int j = 0; j < 8; ++j) dst[j][r] = v[j];
    __syncthreads();
#pragma unroll
    for (int kk = 0; kk < 8; ++kk) {
      float a[8], b[8];
      *(float4*)&a[0] = *(const float4*)&As[kk][tn];
      *(float4*)&a[4] = *(const float4*)&As[kk][tn + 4];
      *(float4*)&b[0] = *(const float4*)&Bs[kk][tm];
      *(float4*)&b[4] = *(const float4*)&Bs[kk][tm + 4];
#pragma unroll
      for (int i = 0; i < 8; ++i)
#pragma unroll
        for (int j = 0; j < 8; ++j) acc[i][j] += a[i] * b[j];
    }
    __syncthreads();
  }
#pragma unroll
  for (int i = 0; i < 8; ++i) {
    int row = bn + tn + i;
    if (row >= N) continue;
#pragma unroll
    for (int j = 0; j < 8; ++j) {
      int col = bm + tm + j;
      if (col < M) C[(size_t)row * M + col] = acc[i][j] + (bias ? bias[col] : 0.0f);
    }
  }
}

// ---------------- sync-free encoder recurrence (r6, unchanged)
__global__ __launch_bounds__(256) void k_enc_rec(
    const float* __restrict__ giF, const float* __restrict__ giB,
    const float* __restrict__ W2, const float* __restrict__ bhh,
    float* __restrict__ y) {
  const int b0 = blockIdx.x * 2;
  const int dir = blockIdx.y;
  const int c = threadIdx.x;
  const float* gi = dir ? giB : giF;
  const v2f* Wv = (const v2f*)(W2 + (size_t)dir * 196608);
  const float* bh = bhh + dir * 768;

  __shared__ __align__(16) float hls[2][2][258];
  for (int i = c; i < 2 * 2 * 258; i += 256) ((float*)hls)[i] = 0.0f;
  __syncthreads();

  const float bhr = bh[c], bhz = bh[256 + c], bhn = bh[512 + c];
  const int tt0 = dir ? 127 : 0;
  const float* g0p = gi + (size_t)tt0 * 49152 + (size_t)b0 * 768;
  float g0r = g0p[c], g0z = g0p[256 + c], g0n = g0p[512 + c];
  float g1r = g0p[768 + c], g1z = g0p[1024 + c], g1n = g0p[1280 + c];

  for (int t = 0; t < 128; ++t) {
    const int cu = t & 1;
    float p0r = 0, p0z = 0, p0n = 0, p1r = 0, p1z = 0, p1n = 0;
    if (t < 127) {
      const int tn_ = dir ? 126 - t : t + 1;
      const float* gp = gi + (size_t)tn_ * 49152 + (size_t)b0 * 768;
      p0r = gp[c]; p0z = gp[256 + c]; p0n = gp[512 + c];
      p1r = gp[768 + c]; p1z = gp[1024 + c]; p1n = gp[1280 + c];
    }
    v2f a0r = {0,0}, a0z = {0,0}, a0n = {0,0};
    v2f a1r = {0,0}, a1z = {0,0}, a1n = {0,0};
    const float* h0p = &hls[cu][0][0];
    const float* h1p = &hls[cu][1][0];
#pragma unroll 4
    for (int kp = 0; kp < 128; ++kp) {
      v2f wr = Wv[kp * 768 + c];
      v2f wz = Wv[kp * 768 + 256 + c];
      v2f wn = Wv[kp * 768 + 512 + c];
      v2f h0 = *(const v2f*)&h0p[kp * 2];
      v2f h1 = *(const v2f*)&h1p[kp * 2];
      a0r += h0 * wr; a0z += h0 * wz; a0n += h0 * wn;
      a1r += h1 * wr; a1z += h1 * wz; a1n += h1 * wn;
    }
    float r0 = sigm(g0r + a0r.x + a0r.y + bhr);
    float z0 = sigm(g0z + a0z.x + a0z.y + bhz);
    float n0 = tanhf(g0n + r0 * (a0n.x + a0n.y + bhn));
    float h0new = (1.f - z0) * n0 + z0 * h0p[c];
    float r1 = sigm(g1r + a1r.x + a1r.y + bhr);
    float z1 = sigm(g1z + a1z.x + a1z.y + bhz);
    float n1 = tanhf(g1n + r1 * (a1n.x + a1n.y + bhn));
    float h1new = (1.f - z1) * n1 + z1 * h1p[c];
    hls[cu ^ 1][0][c] = h0new;
    hls[cu ^ 1][1][c] = h1new;
    const int tw = dir ? 127 - t : t;
    float* yp = y + (size_t)tw * 32768 + (size_t)b0 * 512 + dir * 256 + c;
    yp[0] = h0new;
    yp[512] = h1new;
    g0r = p0r; g0z = p0z; g0n = p0n; g1r = p1r; g1z = p1z; g1n = p1n;
    __syncthreads();
  }
}

// ---------------- hcat[2][64][512]
__global__ __launch_bounds__(256) void k_hcat(const float* __restrict__ x1,
                                              const float* __restrict__ encout,
                                              float* __restrict__ hcat) {
  int i = blockIdx.x * 256 + threadIdx.x;
  int l = i >> 15, r = i & 32767, b = r >> 9, d = r & 511;
  const float* src = l ? encout : x1;
  int ts = (d < 256) ? 127 : 0;
  hcat[i] = src[((size_t)(ts << 6) + b) * 512 + d];
}

// ---------------- decoder GRU cell phase (r6): atl staging + L2-streamed weights
DINL void gru_at(int cb, int tid, const float* __restrict__ xin,
                 const float* __restrict__ hin, float* __restrict__ hout,
                 float* __restrict__ houtT,
                 const float* __restrict__ Wih, const float* __restrict__ Whh,
                 const float* __restrict__ bih, const float* __restrict__ bhh,
                 float* xs, float* hs) {
  const int cchunk = cb % 19, bchunk = cb / 19;
  const int cl = tid & 15, bl = tid >> 4;
  const int c = cchunk * 16 + cl;
  const int b0 = bchunk * 16, bq = b0 + bl;
#pragma unroll 4
  for (int i = tid; i < 4800; i += 256) {
    int row = i / 300, q = i - row * 300;
    xs[i] = atl(xin + (size_t)(b0 + row) * 300 + q);
    hs[i] = atl(hin + (size_t)(b0 + row) * 300 + q);
  }
  __syncthreads();
  if (c < 300) {
    float gir = bih[c], giz = bih[300 + c], gin = bih[600 + c];
    float ghr = bhh[c], ghz = bhh[300 + c], ghn = bhh[600 + c];
    const float4* wir = (const float4*)(Wih + (size_t)c * 300);
    const float4* wiz = (const float4*)(Wih + (size_t)(300 + c) * 300);
    const float4* win = (const float4*)(Wih + (size_t)(600 + c) * 300);
    const float4* whr = (const float4*)(Whh + (size_t)c * 300);
    const float4* whz = (const float4*)(Whh + (size_t)(300 + c) * 300);
    const float4* whn = (const float4*)(Whh + (size_t)(600 + c) * 300);
    const float4* xr = (const float4*)(xs + bl * 300);
    const float4* hr = (const float4*)(hs + bl * 300);
    for (int q = 0; q < 75; ++q) {
      float4 xv = xr[q], hv = hr[q];
      gir += dot4f(xv, wir[q]);
      giz += dot4f(xv, wiz[q]);
      gin += dot4f(xv, win[q]);
      ghr += dot4f(hv, whr[q]);
      ghz += dot4f(hv, whz[q]);
      ghn += dot4f(hv, whn[q]);
    }
    float r = sigm(gir + ghr), z = sigm(giz + ghz);
    float n = tanhf(gin + r * ghn);
    float hnew = (1.f - z) * n + z * hs[bl * 300 + c];
    atsf(&hout[(size_t)bq * 300 + c], hnew);
    if (houtT) atsf(&houtT[(size_t)c * 64 + bq], hnew);
  }
  __syncthreads();
}

// ---------------- persistent decoder: all 32 steps, 256 WGs x 256 threads.
__global__ __launch_bounds__(256) void k_dec_all(
    float* __restrict__ dech, float* __restrict__ h1T, float* __restrict__ xdec,
    ull* __restrict__ bests, unsigned* __restrict__ cnt,
    const float* __restrict__ w1e, const float* __restrict__ encout,
    const float* __restrict__ l2W, const float* __restrict__ l2b,
    const float* __restrict__ l3W, const float* __restrict__ l3b,
    const float* __restrict__ Vatt, const float* __restrict__ embdec,
    const float* __restrict__ dWih, const float* __restrict__ dWhh,
    const float* __restrict__ dbih, const float* __restrict__ dbhh,
    const float* __restrict__ embT, const float* __restrict__ outb,
    float* __restrict__ out) {
  const int wg = blockIdx.x, tid = threadIdx.x;
  __shared__ __align__(16) float smem[27392];  // 19200 (hch/scr) + 8192 (embT dbuf)

  unsigned tgt = 0;
  for (int t = 0; t < 32; ++t) {
    const int cur_ = t & 1;
    float* hc = dech + cur_ * 38400;
    float* hn = dech + (cur_ ^ 1) * 38400;

    // ---- phase 1: attention + x build (wg < 64, one WG per batch)
    if (wg < 64) {
      const int b = wg;
      float* h1s = smem;
      float* w2h = smem + 304;
      float* eXa = smem + 608;
      float* aa  = smem + 1424;
      float* red = smem + 1552;
      ull* redb  = (ull*)(smem + 1680);

      if (tid < 128) {
        ull m = 0ULL;
        if (t > 0) {
          m = atl64(&bests[(size_t)tid * 64 + b]);
          if (tid + 128 < 250) m = umax64(m, atl64(&bests[(size_t)(tid + 128) * 64 + b]));
        }
        redb[tid] = m;
      }
      for (int i = tid; i < 300; i += 256) h1s[i] = atl(hc + 19200 + b * 300 + i);
      __syncthreads();
      for (int s = 64; s > 0; s >>= 1) {
        if (tid < s) redb[tid] = umax64(redb[tid], redb[tid + s]);
        __syncthreads();
      }
      const int ib = (t > 0) ? (int)(~(unsigned)(redb[0] & 0xFFFFFFFFULL)) : 0;

      for (int m = tid; m < 300; m += 256) {
        const float4* wr = (const float4*)(l2W + (size_t)m * 300);
        const float4* hr = (const float4*)h1s;
        float acc = l2b[m];
#pragma unroll 5
        for (int q = 0; q < 75; ++q) acc += dot4f(wr[q], hr[q]);
        w2h[m] = acc;
      }
      __syncthreads();

      if (tid < 128) {
        const float4* wp = (const float4*)(w1e + ((size_t)(tid << 6) + b) * 300);
        const float4* vp = (const float4*)Vatt;
        const float4* hp = (const float4*)w2h;
        float acc = 0.f;
#pragma unroll 5
        for (int q = 0; q < 75; ++q) {
          float4 w = wp[q], h = hp[q], v = vp[q];
          acc += tanhf(w.x + h.x) * v.x + tanhf(w.y + h.y) * v.y +
                 tanhf(w.z + h.z) * v.z + tanhf(w.w + h.w) * v.w;
        }
        aa[tid] = acc;
        red[tid] = acc;
      }
      __syncthreads();
      for (int s = 64; s > 0; s >>= 1) {
        if (tid < s) red[tid] = fmaxf(red[tid], red[tid + s]);
        __syncthreads();
      }
      float mx = red[0];
      __syncthreads();
      if (tid < 128) {
        float ex = expf(aa[tid] - mx);
        aa[tid] = ex;
        red[tid] = ex;
      }
      __syncthreads();
      for (int s = 64; s > 0; s >>= 1) {
        if (tid < s) red[tid] += red[tid + s];
        __syncthreads();
      }
      float inv = 1.0f / red[0];
      __syncthreads();
      if (tid < 128) aa[tid] *= inv;
      for (int d = tid; d < 300; d += 256) eXa[d] = embdec[(size_t)ib * 300 + d];
      __syncthreads();

      for (int d = tid; d < 512; d += 256) {
        const float* ebase = encout + (size_t)b * 512 + d;
        float acc = 0.f;
#pragma unroll 8
        for (int s = 0; s < 128; ++s) acc += aa[s] * ebase[(size_t)s * 32768];
        eXa[300 + d] = acc;
      }
      __syncthreads();

      for (int m = tid; m < 300; m += 256) {
        const float4* wr = (const float4*)(l3W + (size_t)m * 812);
        const float4* xr = (const float4*)eXa;
        float acc = l3b[m];
#pragma unroll 7
        for (int q = 0; q < 203; ++q) acc += dot4f(wr[q], xr[q]);
        atsf(&xdec[b * 300 + m], acc);
      }
      __syncthreads();
    }
    gbar(cnt, 256u * (++tgt), tid);

    // ---- phase 2: GRU cell 0 (wg < 76)
    if (wg < 76)
      gru_at(wg, tid, xdec, hc, hn, nullptr, dWih, dWhh, dbih, dbhh,
             smem, smem + 4800);
    gbar(cnt, 256u * (++tgt), tid);

    // ---- phase 3: GRU cell 1 (wg 76..151, +h1T)
    if (wg >= 76 && wg < 152)
      gru_at(wg - 76, tid, hn, hc + 19200, hn + 19200, h1T,
             dWih + 270000, dWhh + 270000, dbih + 900, dbhh + 900,
             smem, smem + 4800);
    gbar(cnt, 256u * (++tgt), tid);

    // ---- phase 4: logits + argmax partials (wg < 250, 128 v-cols each).
    // embT chunk (32 rows x 128 cols = 16KB) double-buffered via global_load_lds.
    if (wg < 250) {
      const int v0 = wg * 128;
      const int vq = tid & 31, bo = tid >> 5;
      const int wave = tid >> 6, lane = tid & 63;
      float* hch = smem;           // [300][64]
      float* lb  = smem + 19200;   // [2][32][128]

      // stage h1T once (bypass loads, pipelined) + issue chunk 0
#pragma unroll 8
      for (int i = tid; i < 19200; i += 256) hch[i] = atl(h1T + i);
      {
        const float* gb = embT + v0;
#pragma unroll
        for (int j = 0; j < 4; ++j) {
          const int p = wave * 4 + j;                 // row pair 0..15
          const int row = p * 2 + (lane >> 5);
          gl_lds16(gb + (size_t)row * 32000 + ((lane & 31) << 2), lb + p * 256);
        }
      }
      asm volatile("s_waitcnt vmcnt(0)" ::: "memory");
      __syncthreads();

      float acc[8][4] = {};
      int cur = 0;
      for (int kc = 0; kc < 10; ++kc) {
        const int k0 = kc << 5;
        const int nrows = (kc < 9) ? 32 : 12;
        // issue next chunk into the other buffer (fire-and-forget)
        if (kc < 9) {
          const int nrN = (kc + 1 < 9) ? 32 : 12;
          const float* gb = embT + (size_t)(k0 + 32) * 32000 + v0;
          float* lbn = lb + ((cur ^ 1) << 12);
#pragma unroll
          for (int j = 0; j < 4; ++j) {
            const int p = wave * 4 + j;
            if (p * 2 < nrN) {
              const int row = p * 2 + (lane >> 5);
              gl_lds16(gb + (size_t)row * 32000 + ((lane & 31) << 2), lbn + p * 256);
            }
          }
        }
        // compute current chunk from LDS
        const float* eb = lb + (cur << 12);
#pragma unroll 8
        for (int k = 0; k < nrows; ++k) {
          float4 ev = *(const float4*)&eb[(k << 7) + (vq << 2)];
          float4 h0 = *(const float4*)&hch[((k0 + k) << 6) + (bo << 3)];
          float4 h1 = *(const float4*)&hch[((k0 + k) << 6) + (bo << 3) + 4];
          acc[0][0] += h0.x * ev.x; acc[0][1] += h0.x * ev.y;
          acc[0][2] += h0.x * ev.z; acc[0][3] += h0.x * ev.w;
          acc[1][0] += h0.y * ev.x; acc[1][1] += h0.y * ev.y;
          acc[1][2] += h0.y * ev.z; acc[1][3] += h0.y * ev.w;
          acc[2][0] += h0.z * ev.x; acc[2][1] += h0.z * ev.y;
          acc[2][2] += h0.z * ev.z; acc[2][3] += h0.z * ev.w;
          acc[3][0] += h0.w * ev.x; acc[3][1] += h0.w * ev.y;
          acc[3][2] += h0.w * ev.z; acc[3][3] += h0.w * ev.w;
          acc[4][0] += h1.x * ev.x; acc[4][1] += h1.x * ev.y;
          acc[4][2] += h1.x * ev.z; acc[4][3] += h1.x * ev.w;
          acc[5][0] += h1.y * ev.x; acc[5][1] += h1.y * ev.y;
          acc[5][2] += h1.y * ev.z; acc[5][3] += h1.y * ev.w;
          acc[6][0] += h1.z * ev.x; acc[6][1] += h1.z * ev.y;
          acc[6][2] += h1.z * ev.z; acc[6][3] += h1.z * ev.w;
          acc[7][0] += h1.w * ev.x; acc[7][1] += h1.w * ev.y;
          acc[7][2] += h1.w * ev.z; acc[7][3] += h1.w * ev.w;
        }
        asm volatile("s_waitcnt vmcnt(0)" ::: "memory");
        __syncthreads();
        cur ^= 1;
      }

      // epilogue: logits + LDS argmax partials (smem reused as sacc[128][65])
      float* sacc = smem;
      float4 ob = *(const float4*)(outb + v0 + (vq << 2));
      float* outp = out + (size_t)t * 2048000;
#pragma unroll
      for (int i = 0; i < 8; ++i) {
        const int b = (bo << 3) + i;
        float4 r;
        r.x = acc[i][0] + ob.x; r.y = acc[i][1] + ob.y;
        r.z = acc[i][2] + ob.z; r.w = acc[i][3] + ob.w;
        *(float4*)(outp + (size_t)b * 32000 + v0 + (vq << 2)) = r;
        sacc[((vq << 2) + 0) * 65 + b] = r.x;
        sacc[((vq << 2) + 1) * 65 + b] = r.y;
        sacc[((vq << 2) + 2) * 65 + b] = r.z;
        sacc[((vq << 2) + 3) * 65 + b] = r.w;
      }
      __syncthreads();
      if (tid < 64) {
        ull best = 0ULL;
#pragma unroll 4
        for (int v = 0; v < 128; ++v)
          best = umax64(best, packmax(sacc[v * 65 + tid], v0 + v));
        ats64(&bests[(size_t)wg * 64 + tid], best);
      }
      __syncthreads();
    }
    if (t < 31) gbar(cnt, 256u * (++tgt), tid);
  }
}

extern "C" void kernel_launch(void* const* d_in, const int* in_sizes, int n_in,
                              void* d_out_v, int out_size, void* d_ws, size_t ws_size,
                              hipStream_t stream) {
  (void)in_sizes; (void)n_in; (void)out_size; (void)ws_size;
  const float* emb_enc = (const float*)d_in[0];
  const float* eWih0   = (const float*)d_in[1];
  const float* eWhh0   = (const float*)d_in[2];
  const float* ebih0   = (const float*)d_in[3];
  const float* ebhh0   = (const float*)d_in[4];
  const float* eWih1   = (const float*)d_in[5];
  const float* eWhh1   = (const float*)d_in[6];
  const float* ebih1   = (const float*)d_in[7];
  const float* ebhh1   = (const float*)d_in[8];
  const float* Wout    = (const float*)d_in[9];
  const float* emb_dec = (const float*)d_in[10];
  const float* dWih    = (const float*)d_in[11];
  const float* dWhh    = (const float*)d_in[12];
  const float* dbih    = (const float*)d_in[13];
  const float* dbhh    = (const float*)d_in[14];
  const float* W1      = (const float*)d_in[15];
  const float* l2W     = (const float*)d_in[16];
  const float* l2b     = (const float*)d_in[17];
  const float* l3W     = (const float*)d_in[18];
  const float* l3b     = (const float*)d_in[19];
  const float* Vatt    = (const float*)d_in[20];
  const float* outb    = (const float*)d_in[21];
  const int* inp       = (const int*)d_in[22];
  float* d_out = (float*)d_out_v;

  float* ws = (float*)d_ws;
  size_t off = 0;
  auto take = [&](size_t n) { float* p = ws + off; off += (n + 3) & ~(size_t)3; return p; };
  float* embT   = take((size_t)300 * 32000);
  float* encout = take((size_t)8192 * 512);
  float* w1e    = take((size_t)8192 * 300);
  float* W1T    = take((size_t)300 * 512);
  float* hcat   = take((size_t)128 * 512);
  float* dech   = take((size_t)2 * 2 * 64 * 300);
  float* h1T    = take((size_t)300 * 64);
  float* xdec   = take((size_t)64 * 300);
  ull* bests    = (ull*)take((size_t)250 * 64 * 2);
  unsigned* cnt = (unsigned*)take((size_t)32);

  // encoder scratch in d_out (dead before decoder writes)
  float* emb  = d_out;
  float* gi0f = emb + 2457600;
  float* gi0b = gi0f + 6291456;
  float* x1   = gi0b + 6291456;
  float* gi1f = x1 + 4194304;
  float* gi1b = gi1f + 6291456;
  float* W2L0 = d_out + 33554432;
  float* W2L1 = W2L0 + 393216;

  hipMemsetAsync(cnt, 0, 32 * sizeof(unsigned), stream);

  k_embed<<<2400, 256, 0, stream>>>((const float4*)emb_enc, inp, (float4*)emb);
  k_transpose<<<dim3(10, 16), 256, 0, stream>>>(W1, W1T, 512, 300);
  k_transpose<<<dim3(10, 1000), 256, 0, stream>>>(emb_dec, embT, 32000, 300);
  k_packW<<<768, 256, 0, stream>>>(eWhh0, W2L0);
  k_packW<<<768, 256, 0, stream>>>(eWhh1, W2L1);

  // encoder layer 0
  k_gemm128<<<dim3(64, 6), 256, 0, stream>>>(emb, eWih0, ebih0, gi0f, 8192, 768, 300);
  k_gemm128<<<dim3(64, 6), 256, 0, stream>>>(emb, eWih0 + 230400, ebih0 + 768, gi0b, 8192, 768, 300);
  k_enc_rec<<<dim3(32, 2), 256, 0, stream>>>(gi0f, gi0b, W2L0, ebhh0, x1);

  // encoder layer 1
  k_gemm128<<<dim3(64, 6), 256, 0, stream>>>(x1, eWih1, ebih1, gi1f, 8192, 768, 512);
  k_gemm128<<<dim3(64, 6), 256, 0, stream>>>(x1, eWih1 + 393216, ebih1 + 768, gi1b, 8192, 768, 512);
  k_enc_rec<<<dim3(32, 2), 256, 0, stream>>>(gi1f, gi1b, W2L1, ebhh1, encout);

  // encoder epilogue
  k_hcat<<<256, 256, 0, stream>>>(x1, encout, hcat);
  k_gemm128<<<dim3(1, 3), 256, 0, stream>>>(hcat, Wout, nullptr, dech, 128, 300, 512);
  k_gemm128<<<dim3(64, 3), 256, 0, stream>>>(encout, W1T, nullptr, w1e, 8192, 300, 512);

  // persistent decoder
  k_dec_all<<<256, 256, 0, stream>>>(dech, h1T, xdec, bests, cnt,
                                     w1e, encout, l2W, l2b, l3W, l3b,
                                     Vatt, emb_dec, dWih, dWhh, dbih, dbhh,
                                     embT, outb, d_out);
}